// Round 6
// baseline (130820.300 us; speedup 1.0000x reference)
//
#include <hip/hip_runtime.h>

// LayerNorm-LSTM, S=512 B=64 I=H=512 L=2. All I/O f32.
// FULL-F32 correctness version (no bf16 anywhere: the recurrence is
// self-excited (max|c| ~ 488) => chaotic; bf16-rounded W decorrelates the
// trajectory => rounds 4/5's O(1) absmax. f32 keeps noise at fma-order level.)
// One kernel per (layer, timestep), stream-ordered. WG = one batch row.

typedef float f32x4 __attribute__((ext_vector_type(4)));

__device__ __forceinline__ float sigm(float x) { return 1.f / (1.f + __expf(-x)); }
__device__ __forceinline__ float tanh_f(float x) { return 2.f / (1.f + __expf(-2.f * x)) - 1.f; }

__global__ void init_kernel(const float* __restrict__ h0, const float* __restrict__ c0,
                            float* __restrict__ h_ws, float* __restrict__ c_ws) {
  int i = blockIdx.x * 256 + threadIdx.x;
  if (i < 2 * 64 * 512) { h_ws[i] = h0[i]; c_ws[i] = c0[i]; }
}

__global__ __launch_bounds__(256)
void step_kernel(const float* x_src,               // [64][512] (may alias y_dst)
                 const float* __restrict__ wx,     // [512][2048] f32
                 const float* __restrict__ wh,     // [512][2048] f32
                 const float* __restrict__ bias,   // [2048]
                 const float* __restrict__ gamma_, // [2048] (4 gates x 512)
                 const float* __restrict__ beta_,  // [2048]
                 float* __restrict__ h_ws,         // [64][512]
                 float* __restrict__ c_ws,         // [64][512]
                 float* y_dst,                     // [64][512] (may alias x_src)
                 float* __restrict__ hn_dst,       // null unless last step
                 float* __restrict__ cn_dst) {
  __shared__ float A[1024];       // [x_t(512); h(512)]
  __shared__ float sred[512];     // per-thread (s, ss)
  __shared__ float minv[8];       // per-gate (mu, inv)
  __shared__ float gnorm[2048];

  const int tid = threadIdx.x;
  const int b = blockIdx.x;

  for (int i = tid; i < 512; i += 256) A[i] = x_src[b * 512 + i];
  for (int i = tid; i < 512; i += 256) A[512 + i] = h_ws[b * 512 + i];
  __syncthreads();

  const int c0i = tid * 8;        // this thread's 8 gate-cols (one gate: g=tid>>6)
  float acc[8];
#pragma unroll
  for (int j = 0; j < 8; ++j) acc[j] = bias[c0i + j];

  for (int k = 0; k < 512; ++k) {           // x @ wx
    float a = A[k];
    f32x4 w0 = *(const f32x4*)&wx[(size_t)k * 2048 + c0i];
    f32x4 w1 = *(const f32x4*)&wx[(size_t)k * 2048 + c0i + 4];
    acc[0] = fmaf(a, w0[0], acc[0]); acc[1] = fmaf(a, w0[1], acc[1]);
    acc[2] = fmaf(a, w0[2], acc[2]); acc[3] = fmaf(a, w0[3], acc[3]);
    acc[4] = fmaf(a, w1[0], acc[4]); acc[5] = fmaf(a, w1[1], acc[5]);
    acc[6] = fmaf(a, w1[2], acc[6]); acc[7] = fmaf(a, w1[3], acc[7]);
  }
  for (int k = 0; k < 512; ++k) {           // h @ wh
    float a = A[512 + k];
    f32x4 w0 = *(const f32x4*)&wh[(size_t)k * 2048 + c0i];
    f32x4 w1 = *(const f32x4*)&wh[(size_t)k * 2048 + c0i + 4];
    acc[0] = fmaf(a, w0[0], acc[0]); acc[1] = fmaf(a, w0[1], acc[1]);
    acc[2] = fmaf(a, w0[2], acc[2]); acc[3] = fmaf(a, w0[3], acc[3]);
    acc[4] = fmaf(a, w1[0], acc[4]); acc[5] = fmaf(a, w1[1], acc[5]);
    acc[6] = fmaf(a, w1[2], acc[6]); acc[7] = fmaf(a, w1[3], acc[7]);
  }

  // LN stats: thread partial -> LDS -> 4 serial reducers (deterministic)
  {
    float s = 0.f, ss = 0.f;
#pragma unroll
    for (int j = 0; j < 8; ++j) { s += acc[j]; ss += acc[j] * acc[j]; }
    sred[tid * 2] = s; sred[tid * 2 + 1] = ss;
  }
  __syncthreads();
  if (tid < 4) {
    float S = 0.f, SS = 0.f;
    for (int u2 = 0; u2 < 64; ++u2) {
      S += sred[(tid * 64 + u2) * 2];
      SS += sred[(tid * 64 + u2) * 2 + 1];
    }
    float mu = S * (1.f / 512.f);
    float var = SS * (1.f / 512.f) - mu * mu;
    minv[tid * 2] = mu;
    minv[tid * 2 + 1] = rsqrtf(fmaxf(var, 0.f) + 1e-5f);
  }
  __syncthreads();
  {
    int g = tid >> 6;
    float mu = minv[g * 2], inv = minv[g * 2 + 1];
#pragma unroll
    for (int j = 0; j < 8; ++j) {
      int c = c0i + j;
      gnorm[c] = (acc[j] - mu) * inv * gamma_[c] + beta_[c];
    }
  }
  __syncthreads();

  // cell update: 2 h-cols per thread
#pragma unroll
  for (int v = 0; v < 2; ++v) {
    int hc = tid * 2 + v;
    float ig = sigm(gnorm[hc]);
    float fg = sigm(gnorm[512 + hc]);
    float og = sigm(gnorm[1024 + hc]);
    float ug = tanh_f(gnorm[1536 + hc]);
    float cs = fg * c_ws[b * 512 + hc] + ig * ug;
    float hv = og * tanh_f(cs);
    c_ws[b * 512 + hc] = cs;
    h_ws[b * 512 + hc] = hv;
    y_dst[b * 512 + hc] = hv;
    if (hn_dst != nullptr) {
      hn_dst[b * 512 + hc] = hv;
      cn_dst[b * 512 + hc] = cs;
    }
  }
}

extern "C" void kernel_launch(void* const* d_in, const int* in_sizes, int n_in,
                              void* d_out, int out_size, void* d_ws, size_t ws_size,
                              hipStream_t stream) {
  const float* inputs = (const float*)d_in[0];
  const float* h0 = (const float*)d_in[1];
  const float* c0 = (const float*)d_in[2];
  const float* wx0 = (const float*)d_in[3];
  const float* wx1 = (const float*)d_in[4];
  const float* wh0 = (const float*)d_in[5];
  const float* wh1 = (const float*)d_in[6];
  const float* bias = (const float*)d_in[7];
  const float* gamma_ = (const float*)d_in[8];
  const float* beta_ = (const float*)d_in[9];
  float* out = (float*)d_out;

  char* ws = (char*)d_ws;
  float* h_ws = (float*)ws;                 // 256 KB (2 layers)
  float* c_ws = (float*)(ws + 262144);      // 256 KB

  hipLaunchKernelGGL(init_kernel, dim3(256), dim3(256), 0, stream,
                     h0, c0, h_ws, c_ws);

  for (int layer = 0; layer < 2; ++layer) {
    const float* wx = layer ? wx1 : wx0;
    const float* wh = layer ? wh1 : wh0;
    for (int t = 0; t < 512; ++t) {
      const float* x_src = layer ? (out + (size_t)t * 32768)
                                 : (inputs + (size_t)t * 32768);
      float* hn = (t == 511) ? (out + 16777216 + layer * 32768) : nullptr;
      float* cn = (t == 511) ? (out + 16842752 + layer * 32768) : nullptr;
      hipLaunchKernelGGL(step_kernel, dim3(64), dim3(256), 0, stream,
                         x_src, wx, wh,
                         bias + layer * 2048, gamma_ + layer * 2048,
                         beta_ + layer * 2048, h_ws + layer * 32768,
                         c_ws + layer * 32768, out + (size_t)t * 32768, hn, cn);
    }
  }
}

// Round 8
// 48606.894 us; speedup vs baseline: 2.6914x; 2.6914x over previous
//
#include <hip/hip_runtime.h>
#include <hip/hip_cooperative_groups.h>

namespace cg = cooperative_groups;

// LayerNorm-LSTM, S=512 B=64 I=H=512 L=2, all I/O f32, all compute f32
// (recurrence is chaotic: bf16 W => absmax ~1.4 FAIL; f32 ordering noise
//  => ~0.016 PASS. So: f32 VALU only, deterministic reduction orders.)
//
// Persistent cooperative kernel: 256 WGs x 256 thr, 1 WG/CU (158.7 KB LDS).
//   wg = [layer(2)][w(128)]; WG owns rows 0..63 x hc [4w,4w+4) x 4 gates.
//   Per tick: 1024 outputs = [x_t;h](64x1024) @ Wslice(1024x16), W in LDS.
//   4 waves split K (32-chunks), thread tile 4 rows x 4 cols.
//   A staged in 8 chunks of 128 k, double-buffered LDS.
//   Lockstep tau-loop: L0 does t=tau, L1 does t=tau-1. y0 staged via out[t]
//   (L0 writes tick tau, L1 reads+overwrites tick tau+1).
// Sync: cg::grid.sync() x2 per tick (vendor primitive => full cross-XCD
// visibility). Fallback (coop launch failure): monotonic-counter barrier.

#define NTH 256

typedef float f32x4 __attribute__((ext_vector_type(4)));

__device__ __forceinline__ float sigm(float x) { return 1.f / (1.f + __expf(-x)); }
__device__ __forceinline__ float tanh_f(float x) { return 2.f / (1.f + __expf(-2.f * x)) - 1.f; }

__device__ __forceinline__ void gsync(cg::grid_group& g, int use_cg,
                                      unsigned int* bar, unsigned int ev) {
  if (use_cg) { g.sync(); return; }
  __threadfence();
  __syncthreads();
  if (threadIdx.x == 0) {
    __hip_atomic_fetch_add(bar, 1u, __ATOMIC_ACQ_REL, __HIP_MEMORY_SCOPE_AGENT);
    unsigned int tgt = ev * 256u;
    long guard = 0;
    while (__hip_atomic_load(bar, __ATOMIC_ACQUIRE, __HIP_MEMORY_SCOPE_AGENT) < tgt) {
      __builtin_amdgcn_s_sleep(2);
      if (++guard > (1L << 24)) break;
    }
  }
  __syncthreads();
}

__global__ __launch_bounds__(NTH, 1)
void lstm_pk(const float* __restrict__ inputs, const float* __restrict__ h0,
             const float* __restrict__ c0,
             const float* __restrict__ wx0, const float* __restrict__ wx1,
             const float* __restrict__ wh0, const float* __restrict__ wh1,
             const float* __restrict__ bias, const float* __restrict__ gamma_,
             const float* __restrict__ beta_,
             float* __restrict__ out,
             unsigned int* bars,
             float* __restrict__ slots,         // [2][64][4][2][128] f32
             float* __restrict__ h_state,       // [2][64][512] f32
             int use_cg)
{
  cg::grid_group grid = cg::this_grid();

  extern __shared__ float lds[];
  float* W_lds = lds;                   // [1024][16]        16384 f = 64 KB
  float* A_lds = lds + 16384;           // [2][128][68]      17408 f = 68 KB
  float* part  = lds + 16384 + 17408;   // [4][64][17]        4352 f = 17 KB
  float* gates = part + 4352;           // [64][16]           1024 f =  4 KB
  float* minv  = gates + 1024;          // [64][4][2]          512 f =  2 KB
  // total 39680 floats = 158720 B

  const int tid = threadIdx.x;
  const int wg = blockIdx.x;
  const int layer = wg >> 7;
  const int w = wg & 127;            // hc slice [4w, 4w+4)
  const int wavet = tid >> 6;        // K-split group 0..3
  const int lane = tid & 63;
  const int rq = lane & 15;          // row quad -> rows 4rq..4rq+3
  const int gq = lane >> 4;          // gate (col quad)
  const int srow = tid >> 2;         // stats/cell row 0..63
  const int sg = tid & 3;            // stats gate / cell hc-within-slice
  const int hc = 4 * w + sg;         // global h column (cell phase)

  const float* Wx = layer ? wx1 : wx0;
  const float* Wh = layer ? wh1 : wh0;

  // ---- one-time: W slice -> LDS. W_lds[k][g*4+j] = W[k][g*512+4w+j]
  for (int i = 0; i < 16; ++i) {
    int e = tid + i * 256;           // [0,4096)
    int k = e >> 2, g = e & 3;
    const float* src = (k < 512) ? (Wx + (size_t)k * 2048)
                                 : (Wh + (size_t)(k - 512) * 2048);
    f32x4 v = *(const f32x4*)(src + g * 512 + 4 * w);
    *(f32x4*)&W_lds[k * 16 + g * 4] = v;
  }

  f32x4 biasr = *(const f32x4*)(bias + layer * 2048 + sg * 512 + 4 * w);
  float gam[4], bet[4];
#pragma unroll
  for (int g = 0; g < 4; ++g) {
    gam[g] = gamma_[layer * 2048 + g * 512 + hc];
    bet[g] = beta_[layer * 2048 + g * 512 + hc];
  }
  float c_st = c0[layer * 32768 + srow * 512 + hc];

  float* slotL = slots + (size_t)layer * 65536;   // [64][4][2][128]
  float* hstL = h_state + layer * 32768;

  const int strow = rq + 16 * wavet;              // staging row for this thread

  unsigned int ev = 0;

  for (int tau = 0; tau <= 512; ++tau) {
    const int t = layer ? (tau - 1) : tau;
    const bool active = ((unsigned)t < 512u);

    if (active) {
      const float* xsrc = (layer ? out : inputs) + (size_t)t * 32768;
      const float* hsrc = (t == 0) ? (h0 + layer * 32768) : hstL;

      f32x4 acc[4];
#pragma unroll
      for (int r = 0; r < 4; ++r) acc[r] = (f32x4){0.f, 0.f, 0.f, 0.f};

      f32x4 st[8];
      auto LOADC = [&](int c) {            // chunk c: c>=4 -> h, else x
        const float* src = (c >= 4) ? hsrc : xsrc;
        const int koff = (c & 3) * 128;
#pragma unroll
        for (int i = 0; i < 8; ++i) {
          int kq = gq + 4 * i;             // 0..31
          st[i] = *(const f32x4*)(src + strow * 512 + koff + 4 * kq);
        }
      };
      auto WRITEC = [&](int b) {           // regs -> A_lds[b], [k][row]
        float* dst = A_lds + b * 8704;
#pragma unroll
        for (int i = 0; i < 8; ++i) {
          int kq = gq + 4 * i;
#pragma unroll
          for (int j = 0; j < 4; ++j)
            dst[(4 * kq + j) * 68 + strow] = st[i][j];
        }
      };
      auto COMPUTEC = [&](int c, int b) {
        const float* Ab = A_lds + b * 8704;
        const int kg = c * 128 + wavet * 32;
#pragma unroll 8
        for (int kk = 0; kk < 32; ++kk) {
          int k = wavet * 32 + kk;
          f32x4 av = *(const f32x4*)&Ab[k * 68 + 4 * rq];
          f32x4 wv = *(const f32x4*)&W_lds[(kg + kk) * 16 + gq * 4];
          acc[0] += av[0] * wv;
          acc[1] += av[1] * wv;
          acc[2] += av[2] * wv;
          acc[3] += av[3] * wv;
        }
      };

      LOADC(4);                            // h-half first
      WRITEC(0);
      __syncthreads();
#pragma unroll 1
      for (int co = 0; co < 8; ++co) {
        int c = (co + 4) & 7;              // 4,5,6,7,0,1,2,3
        if (co < 7) LOADC((co + 5) & 7);
        COMPUTEC(c, co & 1);
        if (co < 7) WRITEC((co + 1) & 1);
        __syncthreads();
      }

      // partials -> LDS (part[m][row][g*4+c], pad 17)
#pragma unroll
      for (int r = 0; r < 4; ++r)
#pragma unroll
        for (int cc = 0; cc < 4; ++cc)
          part[(wavet * 64 + 4 * rq + r) * 17 + gq * 4 + cc] = acc[r][cc];
      __syncthreads();

      // sum 4 K-groups + bias -> gates LDS + stats partial -> own slot
      {
        f32x4 pre;
#pragma unroll
        for (int cc = 0; cc < 4; ++cc) {
          float v = biasr[cc];
          v += part[(0 * 64 + srow) * 17 + sg * 4 + cc];
          v += part[(1 * 64 + srow) * 17 + sg * 4 + cc];
          v += part[(2 * 64 + srow) * 17 + sg * 4 + cc];
          v += part[(3 * 64 + srow) * 17 + sg * 4 + cc];
          pre[cc] = v;
        }
        *(f32x4*)&gates[srow * 16 + sg * 4] = pre;
        float s = ((pre[0] + pre[1]) + pre[2]) + pre[3];
        float ss = ((pre[0] * pre[0] + pre[1] * pre[1]) + pre[2] * pre[2]) + pre[3] * pre[3];
        slotL[((srow * 4 + sg) * 2 + 0) * 128 + w] = s;
        slotL[((srow * 4 + sg) * 2 + 1) * 128 + w] = ss;
      }
    }

    ++ev; gsync(grid, use_cg, bars, ev);   // barrier A: stats slots complete

    if (active) {
      // deterministic reduce of 128 slices (redundant in every WG, same order)
      {
        const float* sp = slotL + (size_t)(srow * 4 + sg) * 256;
        float S = 0.f, SS = 0.f;
        for (int q = 0; q < 128; q += 4) {
          f32x4 v = *(const f32x4*)&sp[q];
          S = (((S + v[0]) + v[1]) + v[2]) + v[3];
        }
        for (int q = 0; q < 128; q += 4) {
          f32x4 v = *(const f32x4*)&sp[128 + q];
          SS = (((SS + v[0]) + v[1]) + v[2]) + v[3];
        }
        float mu = S * (1.f / 512.f);
        float var = SS * (1.f / 512.f) - mu * mu;
        minv[(srow * 4 + sg) * 2 + 0] = mu;
        minv[(srow * 4 + sg) * 2 + 1] = rsqrtf(fmaxf(var, 0.f) + 1e-5f);
      }
      __syncthreads();

      // normalize + cell (thread owns (srow, hc))
      {
        float gv[4];
#pragma unroll
        for (int g = 0; g < 4; ++g) {
          float pre = gates[srow * 16 + g * 4 + sg];
          gv[g] = (pre - minv[(srow * 4 + g) * 2]) * minv[(srow * 4 + g) * 2 + 1] * gam[g] + bet[g];
        }
        float ig = sigm(gv[0]);
        float fg = sigm(gv[1]);
        float og = sigm(gv[2]);
        float ug = tanh_f(gv[3]);
        c_st = fg * c_st + ig * ug;
        float hv = og * tanh_f(c_st);
        hstL[srow * 512 + hc] = hv;
        out[(size_t)t * 32768 + srow * 512 + hc] = hv;  // L0: y0 stage; L1: final
        if (t == 511) {
          out[16777216 + layer * 32768 + srow * 512 + hc] = hv;    // h_n
          out[16842752 + layer * 32768 + srow * 512 + hc] = c_st;  // c_n
        }
      }
    }

    ++ev; gsync(grid, use_cg, bars, ev);   // barrier B: h / y0 published
  }
}

extern "C" void kernel_launch(void* const* d_in, const int* in_sizes, int n_in,
                              void* d_out, int out_size, void* d_ws, size_t ws_size,
                              hipStream_t stream) {
  const float* inputs = (const float*)d_in[0];
  const float* h0 = (const float*)d_in[1];
  const float* c0 = (const float*)d_in[2];
  const float* wx0 = (const float*)d_in[3];
  const float* wx1 = (const float*)d_in[4];
  const float* wh0 = (const float*)d_in[5];
  const float* wh1 = (const float*)d_in[6];
  const float* bias = (const float*)d_in[7];
  const float* gamma_ = (const float*)d_in[8];
  const float* beta_ = (const float*)d_in[9];
  float* out = (float*)d_out;

  char* ws = (char*)d_ws;
  unsigned int* bars = (unsigned int*)ws;         // 4096 B (fallback ctr)
  float* slots = (float*)(ws + 4096);             // 524288 B
  float* h_state = (float*)(ws + 4096 + 524288);  // 262144 B

  const int smem_bytes = 158720;
  hipFuncSetAttribute((const void*)lstm_pk,
                      hipFuncAttributeMaxDynamicSharedMemorySize, smem_bytes);
  hipMemsetAsync(ws, 0, 4096, stream);            // fallback barrier counter

  int use_cg = 1;
  void* args[] = {
      (void*)&inputs, (void*)&h0, (void*)&c0, (void*)&wx0, (void*)&wx1,
      (void*)&wh0, (void*)&wh1, (void*)&bias, (void*)&gamma_, (void*)&beta_,
      (void*)&out, (void*)&bars, (void*)&slots, (void*)&h_state, (void*)&use_cg};
  hipError_t e = hipLaunchCooperativeKernel((const void*)lstm_pk, dim3(256),
                                            dim3(NTH), args, smem_bytes, stream);
  if (e != hipSuccess) {
    use_cg = 0;  // fallback: homemade 256-WG barrier (co-residency by LDS fit)
    hipLaunchKernelGGL(lstm_pk, dim3(256), dim3(NTH), smem_bytes, stream,
                       inputs, h0, c0, wx0, wx1, wh0, wh1, bias, gamma_, beta_,
                       out, bars, slots, h_state, use_cg);
  }
}